// Round 12
// baseline (205.008 us; speedup 1.0000x reference)
//
#include <hip/hip_runtime.h>
#include <hip/hip_bf16.h>

typedef short short8 __attribute__((ext_vector_type(8)));
typedef float floatx4 __attribute__((ext_vector_type(4)));

#define NGROUP 512
#define RREG 256
#define D 512
#define ROWS 131072
#define FBAR_ELEMS (NGROUP * D)   // 262144
#define TROWS 64                  // rows per tile
#define NTILE 4                   // tiles per block
#define GRID (ROWS / (TROWS * NTILE))   // 512 blocks

__device__ __forceinline__ unsigned short f2bf(float f) {
    unsigned int u = __float_as_uint(f);
    unsigned int r = (u + 0x7fffu + ((u >> 16) & 1u)) >> 16;
    return (unsigned short)r;
}
__device__ __forceinline__ float fast_tanh(float x) {
    float cx = fminf(fmaxf(x, -9.5f), 9.5f);
    float e  = __builtin_amdgcn_exp2f(cx * 2.8853900817779268f);  // e^{2cx}
    return (e - 1.f) * __builtin_amdgcn_rcpf(e + 1.f);
}

// ---- kernel 1: W1 fp32 -> bf16, K-CHUNKED PRE-SWIZZLED layout (R10 verbatim) ----
// W1c = 16 chunks of 32 KiB. Chunk kc holds k in [kc*32,kc*32+32) for all 512
// cols: element (col, kc*32+kl) at chunk byte col*64 + ((kl*2) ^ ((col&3)<<4)).
__global__ __launch_bounds__(256) void conv_w1(const float* __restrict__ W1,
                                               unsigned short* __restrict__ W1c) {
    int tid = blockIdx.x * 256 + threadIdx.x;   // 0..65535
    int P = tid * 8;                            // byte offset in 512 KiB image
    int kc = P >> 15;
    int L = P & 32767;
    int col = L >> 6;
    int q = L & 63;
    int kl = (q ^ ((col & 3) << 4)) >> 1;       // multiple of 4
    const float* src = W1 + col * 512 + kc * 32 + kl;
    float4 v = *reinterpret_cast<const float4*>(src);
    ushort4 o;
    o.x = f2bf(v.x); o.y = f2bf(v.y); o.z = f2bf(v.z); o.w = f2bf(v.w);
    *reinterpret_cast<ushort4*>((char*)W1c + P) = o;
}

// ---- kernel 2: persistent-tile score GEMM ----
// 512 blocks x 512 threads (8 waves). Block = 4 sequential 64-row tiles.
// Per tile: barrier-free K-loop (wave-private 2-buf B DMA, dist-1 prefetch,
// counted vmcnt(4) - never a mid-loop full drain); epilogue writes per-wave
// PARTIAL scores to global (summed in pool kernel - no scorebuf barrier);
// next tile's x loaded mid-epilogue (after acc[0..1] die -> no reg blowup),
// drained by bar1; pack into single A buffer; bar2. HBM x-loads now issue
// once per ~6k-cycle tile instead of once per block (R10 lesson: 8% HBM
// duty cycle was the bound).
__global__ __launch_bounds__(512, 1) void score_gemm(
    const float* __restrict__ x, const unsigned short* __restrict__ W1c,
    const float* __restrict__ b1, const float* __restrict__ W2v,
    float* __restrict__ inv_norm, float* __restrict__ scorespart) {

    __shared__ unsigned short A_lds[TROWS * 512];   // 64 KiB, swizzled, single buf
    __shared__ char B_lds[2][8][4096];              // 64 KiB: [buf][wave][64-col slice]
    __shared__ float inv_s[TROWS];

    const int t = threadIdx.x;
    const int lane = t & 63;
    const int w = t >> 6;          // wave 0..7
    const int cl = lane & 15;
    const int hi = lane >> 4;
    const size_t brow0 = (size_t)blockIdx.x * (TROWS * NTILE);

    // wave-private B stage: chunk kc's 64-col slice for wave w -> B_lds[buf][w]
    auto stageB = [&](int buf, int kc) {
        const char* gb = (const char*)W1c + kc * 32768 + w * 4096 + lane * 16;
        char* lb = &B_lds[buf][w][0];
        #pragma unroll
        for (int i = 0; i < 4; ++i) {
            __builtin_amdgcn_global_load_lds(
                (const __attribute__((address_space(1))) void*)(gb + i * 1024),
                (__attribute__((address_space(3))) void*)(lb + i * 1024),
                16, 0, 0);
        }
    };

    // A staging geometry: lane owns row pr = t>>3, float cols (t&7)*64..+64
    const int pr = t >> 3;
    const int c0 = (t & 7) * 64;            // float col base
    float4 xv[16];

    auto loadX = [&](size_t trow0) {
        const float* xb = x + (trow0 + pr) * (size_t)D + c0;
        #pragma unroll
        for (int j = 0; j < 16; ++j)
            xv[j] = *reinterpret_cast<const float4*>(xb + j * 4);
    };
    auto packA = [&](size_t trow0) {
        float ss = 0.f;
        #pragma unroll
        for (int j = 0; j < 16; ++j)
            ss += xv[j].x*xv[j].x + xv[j].y*xv[j].y + xv[j].z*xv[j].z + xv[j].w*xv[j].w;
        ss += __shfl_xor(ss, 1, 8);
        ss += __shfl_xor(ss, 2, 8);
        ss += __shfl_xor(ss, 4, 8);
        float inv = 1.0f / fmaxf(sqrtf(ss), 1e-12f);
        if ((t & 7) == 0) { inv_s[pr] = inv; inv_norm[trow0 + pr] = inv; }
        const int swz = (pr & 7) << 4;
        #pragma unroll
        for (int q = 0; q < 8; ++q) {
            float4 p = xv[2 * q], r = xv[2 * q + 1];
            short8 pk;
            pk[0] = (short)f2bf(p.x); pk[1] = (short)f2bf(p.y);
            pk[2] = (short)f2bf(p.z); pk[3] = (short)f2bf(p.w);
            pk[4] = (short)f2bf(r.x); pk[5] = (short)f2bf(r.y);
            pk[6] = (short)f2bf(r.z); pk[7] = (short)f2bf(r.w);
            *reinterpret_cast<short8*>(
                (char*)A_lds + pr * 1024 + (((t & 7) * 128 + q * 16) ^ swz)) = pk;
        }
    };

    // ---- prologue: tile 0 ----
    stageB(0, 0);
    stageB(1, 1);
    loadX(brow0);
    packA(brow0);
    __syncthreads();

    const int aswz = (cl & 7) << 4;
    const int bofs = (hi * 16) ^ ((cl & 3) << 4);

    for (int tile = 0; tile < NTILE; ++tile) {
        const size_t trow0 = brow0 + (size_t)tile * TROWS;

        // ---- K loop: 16 steps of 32 k; barrier-free, wave-private ----
        floatx4 acc[4][4];
        #pragma unroll
        for (int tt = 0; tt < 4; ++tt)
            #pragma unroll
            for (int f = 0; f < 4; ++f) acc[tt][f] = floatx4{0, 0, 0, 0};

        #pragma unroll 4
        for (int s = 0; s < 16; ++s) {
            if (s < 15) {
                stageB((s + 1) & 1, s + 1);                  // dist-1 prefetch
                asm volatile("s_waitcnt vmcnt(4)" ::: "memory");   // B(s) done
            } else {
                asm volatile("s_waitcnt vmcnt(0)" ::: "memory");   // B(15) done
            }
            const char* Bb = &B_lds[s & 1][w][0];
            short8 bfr[4], afr[4];
            #pragma unroll
            for (int f = 0; f < 4; ++f)
                bfr[f] = *reinterpret_cast<const short8*>(Bb + (f * 16 + cl) * 64 + bofs);
            #pragma unroll
            for (int tt = 0; tt < 4; ++tt)
                afr[tt] = *reinterpret_cast<const short8*>(
                    (char*)A_lds + (tt * 16 + cl) * 1024 + ((s * 64 + hi * 16) ^ aswz));
            #pragma unroll
            for (int tt = 0; tt < 4; ++tt)
                #pragma unroll
                for (int f = 0; f < 4; ++f)
                    acc[tt][f] = __builtin_amdgcn_mfma_f32_16x16x32_bf16(
                        afr[tt], bfr[f], acc[tt][f], 0, 0, 0);
        }

        // issue next tile's first two B chunks (drain at bar1, overlapped by epilogue)
        if (tile < NTILE - 1) { stageB(0, 0); stageB(1, 1); }

        // ---- epilogue part 1 (tt = 0,1): inv, tanh, w2-dot ----
        float sp[4][4];
        float4 iv4[4];
        #pragma unroll
        for (int tt = 0; tt < 4; ++tt) {
            iv4[tt] = *reinterpret_cast<const float4*>(&inv_s[tt * 16 + hi * 4]);
            #pragma unroll
            for (int i = 0; i < 4; ++i) sp[tt][i] = 0.f;
        }
        #pragma unroll
        for (int f = 0; f < 4; ++f) {
            int col = w * 64 + f * 16 + cl;
            float wv = W2v[col];
            float bb = b1[col];
            #pragma unroll
            for (int tt = 0; tt < 2; ++tt) {
                sp[tt][0] += wv * fast_tanh(acc[tt][f][0] * iv4[tt].x + bb);
                sp[tt][1] += wv * fast_tanh(acc[tt][f][1] * iv4[tt].y + bb);
                sp[tt][2] += wv * fast_tanh(acc[tt][f][2] * iv4[tt].z + bb);
                sp[tt][3] += wv * fast_tanh(acc[tt][f][3] * iv4[tt].w + bb);
            }
        }

        // ---- issue next tile's x loads (acc[0..1] now dead) ----
        if (tile < NTILE - 1) loadX(trow0 + TROWS);

        // ---- epilogue part 2 (tt = 2,3) ----
        #pragma unroll
        for (int f = 0; f < 4; ++f) {
            int col = w * 64 + f * 16 + cl;
            float wv = W2v[col];
            float bb = b1[col];
            #pragma unroll
            for (int tt = 2; tt < 4; ++tt) {
                sp[tt][0] += wv * fast_tanh(acc[tt][f][0] * iv4[tt].x + bb);
                sp[tt][1] += wv * fast_tanh(acc[tt][f][1] * iv4[tt].y + bb);
                sp[tt][2] += wv * fast_tanh(acc[tt][f][2] * iv4[tt].z + bb);
                sp[tt][3] += wv * fast_tanh(acc[tt][f][3] * iv4[tt].w + bb);
            }
        }

        // reduce over 16 col-lanes; store per-wave PARTIAL scores to global
        #pragma unroll
        for (int tt = 0; tt < 4; ++tt) {
            #pragma unroll
            for (int i = 0; i < 4; ++i) {
                float v = sp[tt][i];
                v += __shfl_xor(v, 1, 64);
                v += __shfl_xor(v, 2, 64);
                v += __shfl_xor(v, 4, 64);
                v += __shfl_xor(v, 8, 64);
                if (cl == 0)
                    scorespart[(size_t)w * ROWS + trow0 + tt * 16 + hi * 4 + i] = v;
            }
        }

        __syncthreads();                         // bar1: A reads done; x/B' drained
        if (tile < NTILE - 1) packA(trow0 + TROWS);
        __syncthreads();                         // bar2: new A (+inv_s) visible
    }
}

// ---- kernel 3: softmax over r (summing 8 partials) + fp32 weighted pooling ----
__global__ __launch_bounds__(512) void softmax_pool(
    const float* __restrict__ x, const float* __restrict__ inv_norm,
    const float* __restrict__ scorespart, float* __restrict__ out) {

    __shared__ float F[RREG];
    __shared__ float wts[RREG];
    const int t = threadIdx.x;
    const int g = blockIdx.x;

    float s = 0.f, e = 0.f;
    if (t < RREG) {
        #pragma unroll
        for (int q = 0; q < 8; ++q)
            s += scorespart[(size_t)q * ROWS + (size_t)g * RREG + t];
        F[t] = s;
    }
    __syncthreads();
    for (int off = 128; off > 0; off >>= 1) {
        if (t < off) F[t] = fmaxf(F[t], F[t + off]);
        __syncthreads();
    }
    float mx = F[0];
    __syncthreads();
    if (t < RREG) { e = expf(s - mx); F[t] = e; }
    __syncthreads();
    for (int off = 128; off > 0; off >>= 1) {
        if (t < off) F[t] += F[t + off];
        __syncthreads();
    }
    float denom = F[0];
    if (t < RREG) {
        float al = e / denom;
        out[FBAR_ELEMS + (size_t)g * RREG + t] = al;          // output 1: alphas
        wts[t] = al * inv_norm[(size_t)g * RREG + t];
    }
    __syncthreads();

    // fbar[d=t] = sum_r (alpha_r * inv_r) * x[g,r,t]  (coalesced 2 KB/row)
    float a = 0.f;
    const float* xb = x + (size_t)g * RREG * D + t;
    #pragma unroll 16
    for (int r = 0; r < RREG; ++r) a += wts[r] * xb[(size_t)r * D];
    out[(size_t)g * D + t] = a;                               // output 0: fbar
}

extern "C" void kernel_launch(void* const* d_in, const int* in_sizes, int n_in,
                              void* d_out, int out_size, void* d_ws, size_t ws_size,
                              hipStream_t stream) {
    const float* x  = (const float*)d_in[0];
    const float* W1 = (const float*)d_in[1];
    const float* b1 = (const float*)d_in[2];
    const float* w2 = (const float*)d_in[3];
    // b2 (d_in[4]) shifts all scores uniformly -> softmax-invariant -> unused.
    float* out = (float*)d_out;

    unsigned short* W1c  = (unsigned short*)d_ws;                    // 512 KiB
    float* inv_norm      = (float*)((char*)d_ws + 524288);           // 512 KiB
    float* scorespart    = (float*)((char*)d_ws + 1048576);          // 4 MiB (8 partials)

    conv_w1<<<256, 256, 0, stream>>>(W1, W1c);
    score_gemm<<<GRID, 512, 0, stream>>>(x, W1c, b1, w2, inv_norm, scorespart);
    softmax_pool<<<NGROUP, 512, 0, stream>>>(x, inv_norm, scorespart, out);
}

// Round 13
// 188.825 us; speedup vs baseline: 1.0857x; 1.0857x over previous
//
#include <hip/hip_runtime.h>
#include <hip/hip_bf16.h>

typedef short short8 __attribute__((ext_vector_type(8)));
typedef float floatx4 __attribute__((ext_vector_type(4)));

#define NGROUP 512
#define RREG 256
#define D 512
#define ROWS 131072
#define FBAR_ELEMS (NGROUP * D)   // 262144

__device__ __forceinline__ unsigned short f2bf(float f) {
    unsigned int u = __float_as_uint(f);
    unsigned int r = (u + 0x7fffu + ((u >> 16) & 1u)) >> 16;
    return (unsigned short)r;
}
__device__ __forceinline__ float fast_tanh(float x) {
    float cx = fminf(fmaxf(x, -9.5f), 9.5f);
    float e  = __builtin_amdgcn_exp2f(cx * 2.8853900817779268f);  // e^{2cx}
    return (e - 1.f) * __builtin_amdgcn_rcpf(e + 1.f);
}

// ---- kernel 1: W1 fp32 -> bf16, PRE-SWIZZLED 64-col full-K chunks (R2-proven) ----
// Chunk nc (64 cols x 512 k): LDS image byte L holds
// W1bf[col = nc*64 + L/1024][k elem ((L%1024) ^ ((col&7)<<4))/2].
// Stored linearly so global_load_lds (linear dest) reproduces the swizzled image.
__global__ __launch_bounds__(256) void conv_w1(const float* __restrict__ W1,
                                               unsigned short* __restrict__ W1s) {
    int tid = blockIdx.x * 256 + threadIdx.x;   // 0..65535
    int G = tid * 8;                            // byte offset in 512 KiB
    int nc = G >> 16;
    int L = G & 65535;
    int col_local = L >> 10;
    int sw = L & 1023;
    int k16 = (sw ^ ((col_local & 7) << 4)) >> 4;
    int j0 = (sw & 15) >> 1;                    // 0 or 4
    int col = nc * 64 + col_local;
    const float* src = W1 + col * 512 + k16 * 8 + j0;
    float4 v = *reinterpret_cast<const float4*>(src);
    ushort4 o;
    o.x = f2bf(v.x); o.y = f2bf(v.y); o.z = f2bf(v.z); o.w = f2bf(v.w);
    *reinterpret_cast<ushort4*>((char*)W1s + G) = o;
}

// ---- kernel 2: score GEMM — register-A, streamed-B ----
// 1024 blocks x 512 threads (8 waves). Block = 128 rows; wave owns 16 rows x
// all 512 cols. A loaded DIRECT from global x in MFMA fragment layout
// (lane(cl,hi) frag c: row cl, k=c*32+hi*8; 4 hi-lanes = one 128B line ->
// coalesced), converted to bf16 into a[16] (64 VGPR). NO A-LDS, NO staging
// phase, NO pack on the critical path (R5-R12 lesson: that phase + its
// barriers was the exposed-latency core). B: 64-col full-K chunks DMA'd into
// 2x64 KB LDS dbuf; one barrier/chunk, issued a full iteration (~4k cyc)
// before its drain -> zero stall. K-loop: 4 bank-uniform ds_read_b128 + 4
// MFMA per step; acc folded into score partials per chunk (16 VGPR acc).
__global__ __launch_bounds__(512, 2) void score_gemm(
    const float* __restrict__ x, const unsigned short* __restrict__ W1s,
    const float* __restrict__ b1, const float* __restrict__ W2v,
    float* __restrict__ inv_norm, float* __restrict__ scores) {

    __shared__ unsigned short B_lds[2][32768];   // 2 x 64 KiB

    const int t = threadIdx.x;
    const int lane = t & 63;
    const int w = t >> 6;          // wave 0..7
    const int cl = lane & 15;
    const int hi = lane >> 4;
    const size_t row0 = (size_t)blockIdx.x * 128;

    // cooperative stage of one 64-col chunk (64 KB): 8 KB per wave
    auto stage = [&](int buf, int nc) {
        const char* gb = (const char*)W1s + nc * 65536 + w * 8192 + lane * 16;
        char* lb = (char*)B_lds[buf] + w * 8192;
        #pragma unroll
        for (int i = 0; i < 8; ++i) {
            __builtin_amdgcn_global_load_lds(
                (const __attribute__((address_space(1))) void*)(gb + i * 1024),
                (__attribute__((address_space(3))) void*)(lb + i * 1024),
                16, 0, 0);
        }
    };

    stage(0, 0);   // both chunks in flight during the A-load phase
    stage(1, 1);

    // ---- A: load 16 frags direct from x, bf16-pack, accumulate ss ----
    short8 a[16];
    float ss = 0.f;
    {
        const float* xp = x + (row0 + w * 16 + cl) * (size_t)D + hi * 8;
        #pragma unroll
        for (int c = 0; c < 16; ++c) {
            float4 p = *reinterpret_cast<const float4*>(xp + c * 32);
            float4 q = *reinterpret_cast<const float4*>(xp + c * 32 + 4);
            ss += p.x*p.x + p.y*p.y + p.z*p.z + p.w*p.w
                + q.x*q.x + q.y*q.y + q.z*q.z + q.w*q.w;
            short8 s8;
            s8[0] = (short)f2bf(p.x); s8[1] = (short)f2bf(p.y);
            s8[2] = (short)f2bf(p.z); s8[3] = (short)f2bf(p.w);
            s8[4] = (short)f2bf(q.x); s8[5] = (short)f2bf(q.y);
            s8[6] = (short)f2bf(q.z); s8[7] = (short)f2bf(q.w);
            a[c] = s8;
        }
    }
    // row cl's total lives in lanes {cl, cl+16, cl+32, cl+48}
    ss += __shfl_xor(ss, 16, 64);
    ss += __shfl_xor(ss, 32, 64);
    const float inv = 1.0f / fmaxf(sqrtf(ss), 1e-12f);
    if (lane < 16) inv_norm[row0 + w * 16 + cl] = inv;
    // accumulator row r = hi*4+i needs inv of row r (held by lane cl=r)
    float ivr[4];
    #pragma unroll
    for (int i = 0; i < 4; ++i) ivr[i] = __shfl(inv, hi * 4 + i, 16);

    __syncthreads();   // chunk 0 (and 1) landed

    // ---- loop over 8 col-chunks; fold tanh + w2-dot per chunk ----
    float sp[4] = {0.f, 0.f, 0.f, 0.f};

    for (int nc = 0; nc < 8; ++nc) {
        const char* Bb = (const char*)B_lds[nc & 1];
        floatx4 acc[4];
        #pragma unroll
        for (int f = 0; f < 4; ++f) acc[f] = floatx4{0, 0, 0, 0};

        #pragma unroll
        for (int s = 0; s < 16; ++s) {
            short8 bfr[4];
            #pragma unroll
            for (int f = 0; f < 4; ++f) {
                const int bcol = f * 16 + cl;
                bfr[f] = *reinterpret_cast<const short8*>(
                    Bb + bcol * 1024 + ((s * 64 + hi * 16) ^ ((bcol & 7) << 4)));
            }
            #pragma unroll
            for (int f = 0; f < 4; ++f)
                acc[f] = __builtin_amdgcn_mfma_f32_16x16x32_bf16(
                    a[s], bfr[f], acc[f], 0, 0, 0);
        }

        #pragma unroll
        for (int f = 0; f < 4; ++f) {
            int col = nc * 64 + f * 16 + cl;
            float wv = W2v[col];
            float bb = b1[col];
            #pragma unroll
            for (int i = 0; i < 4; ++i)
                sp[i] += wv * fast_tanh(acc[f][i] * ivr[i] + bb);
        }

        __syncthreads();                      // all waves done with this buffer;
                                              // prev prefetch drained (issued 1 iter ago)
        if (nc + 2 < 8) stage(nc & 1, nc + 2);   // refill the buffer just freed
    }

    // ---- reduce score partials over the 16 col-lanes; C/D row = hi*4+i ----
    #pragma unroll
    for (int i = 0; i < 4; ++i) {
        float v = sp[i];
        v += __shfl_xor(v, 1, 64);
        v += __shfl_xor(v, 2, 64);
        v += __shfl_xor(v, 4, 64);
        v += __shfl_xor(v, 8, 64);
        if (cl == 0) scores[row0 + w * 16 + hi * 4 + i] = v;
    }
}

// ---- kernel 3: softmax over r + fp32 weighted pooling (R10 verbatim) ----
__global__ __launch_bounds__(512) void softmax_pool(
    const float* __restrict__ x, const float* __restrict__ inv_norm,
    const float* __restrict__ scores, float* __restrict__ out) {

    __shared__ float F[RREG];
    __shared__ float wts[RREG];
    const int t = threadIdx.x;
    const int g = blockIdx.x;

    float s = 0.f, e = 0.f;
    if (t < RREG) { s = scores[g * RREG + t]; F[t] = s; }
    __syncthreads();
    for (int off = 128; off > 0; off >>= 1) {
        if (t < off) F[t] = fmaxf(F[t], F[t + off]);
        __syncthreads();
    }
    float mx = F[0];
    __syncthreads();
    if (t < RREG) { e = expf(s - mx); F[t] = e; }
    __syncthreads();
    for (int off = 128; off > 0; off >>= 1) {
        if (t < off) F[t] += F[t + off];
        __syncthreads();
    }
    float denom = F[0];
    if (t < RREG) {
        float al = e / denom;
        out[FBAR_ELEMS + (size_t)g * RREG + t] = al;          // output 1: alphas
        wts[t] = al * inv_norm[(size_t)g * RREG + t];
    }
    __syncthreads();

    // fbar[d=t] = sum_r (alpha_r * inv_r) * x[g,r,t]  (coalesced 2 KB/row)
    float a = 0.f;
    const float* xb = x + (size_t)g * RREG * D + t;
    #pragma unroll 16
    for (int r = 0; r < RREG; ++r) a += wts[r] * xb[(size_t)r * D];
    out[(size_t)g * D + t] = a;                               // output 0: fbar
}

extern "C" void kernel_launch(void* const* d_in, const int* in_sizes, int n_in,
                              void* d_out, int out_size, void* d_ws, size_t ws_size,
                              hipStream_t stream) {
    const float* x  = (const float*)d_in[0];
    const float* W1 = (const float*)d_in[1];
    const float* b1 = (const float*)d_in[2];
    const float* w2 = (const float*)d_in[3];
    // b2 (d_in[4]) shifts all scores uniformly -> softmax-invariant -> unused.
    float* out = (float*)d_out;

    unsigned short* W1s = (unsigned short*)d_ws;                     // 512 KiB
    float* inv_norm = (float*)((char*)d_ws + 524288);                // 512 KiB
    float* scores   = (float*)((char*)d_ws + 1048576);               // 512 KiB

    conv_w1<<<256, 256, 0, stream>>>(W1, W1s);
    score_gemm<<<ROWS / 128, 512, 0, stream>>>(x, W1s, b1, w2, inv_norm, scores);
    softmax_pool<<<NGROUP, 512, 0, stream>>>(x, inv_norm, scores, out);
}